// Round 7
// baseline (80.042 us; speedup 1.0000x reference)
//
#include <hip/hip_runtime.h>
#include <hip/hip_bf16.h>

// Problem constants
#define BB 2
#define CC 512
#define NN 2048          // T*H*W = 8*16*16
#define NHEADS 8
#define HDIM 64
#define NSPLIT 2
#define KVHALF 1024      // NN / NSPLIT

typedef __attribute__((ext_vector_type(8))) __bf16 bf16x8;
typedef __attribute__((ext_vector_type(4))) __bf16 bf16x4;
typedef __attribute__((ext_vector_type(2))) __bf16 bf16x2;
typedef __attribute__((ext_vector_type(4))) float f32x4;

#define QSCALE 0.18033688f  // 0.125 * log2(e): QK^T lands in exp2 domain

// ---------------------------------------------------------------------------
// Kernel 1: LayerNorm statistics. 256 blocks x 16 tokens.
// ---------------------------------------------------------------------------
__global__ __launch_bounds__(256) void ln_stats_kernel(
    const float* __restrict__ x, float* __restrict__ mu, float* __restrict__ rstd) {
  __shared__ float rs[16][16];
  __shared__ float rq[16][16];
  int tl = threadIdx.x & 15;   // token within block
  int cg = threadIdx.x >> 4;   // channel group (32 ch each)
  int tok = blockIdx.x * 16 + tl;
  int b = tok >> 11;
  int n = tok & (NN - 1);
  const float* xp = x + (size_t)b * CC * NN + n;
  float s = 0.f, ss = 0.f;
  int c0 = cg * 32;
#pragma unroll 8
  for (int c = c0; c < c0 + 32; ++c) {
    float v = xp[(size_t)c * NN];
    s += v;
    ss += v * v;
  }
  rs[cg][tl] = s;
  rq[cg][tl] = ss;
  __syncthreads();
  if (threadIdx.x < 16) {
    int t = threadIdx.x;
    float S = 0.f, SS = 0.f;
#pragma unroll
    for (int gidx = 0; gidx < 16; ++gidx) {
      S += rs[gidx][t];
      SS += rq[gidx][t];
    }
    float m = S * (1.0f / CC);
    float var = SS * (1.0f / CC) - m * m;
    int tk = blockIdx.x * 16 + t;
    mu[tk] = m;
    rstd[tk] = rsqrtf(var + 1e-5f);
  }
}

// ---------------------------------------------------------------------------
// Kernel 1b: LN apply + transpose: x[b][c][n] fp32 -> xln_t[b][n][c] bf16.
// ---------------------------------------------------------------------------
__global__ __launch_bounds__(256) void ln_transpose_kernel(
    const float* __restrict__ x, const float* __restrict__ mu,
    const float* __restrict__ rstd, const float* __restrict__ lnw,
    const float* __restrict__ lnb, __bf16* __restrict__ xln_t) {
  __shared__ float Xs[64][68];
  int n0 = blockIdx.x * 64;
  int c0 = blockIdx.y * 64;
  int b = blockIdx.z;
  int tid = threadIdx.x;
#pragma unroll
  for (int l = 0; l < 4; ++l) {
    int e = tid + 256 * l;
    int row = e >> 4, c4 = e & 15;
    float4 v = *(const float4*)&x[((size_t)b * CC + c0 + row) * NN + n0 + c4 * 4];
    *(float4*)&Xs[row][c4 * 4] = v;
  }
  __syncthreads();
  int sr = tid >> 2;
  int sc = (tid & 3) * 16;
  int tok = b * NN + n0 + sr;
  float mun = mu[tok], rsn = rstd[tok];
  __bf16 outv[16];
#pragma unroll
  for (int j = 0; j < 16; ++j) {
    int c = c0 + sc + j;
    outv[j] = (__bf16)((Xs[sc + j][sr] - mun) * rsn * lnw[c] + lnb[c]);
  }
  __bf16* dst = &xln_t[((size_t)b * NN + n0 + sr) * CC + c0 + sc];
  *(bf16x8*)&dst[0] = *(bf16x8*)&outv[0];
  *(bf16x8*)&dst[8] = *(bf16x8*)&outv[8];
}

// ---------------------------------------------------------------------------
// Kernel 2: merged QKV GEMM, bf16 MFMA, reg-staged double-buffered LDS,
// ONE barrier per K-step. blockIdx.y<16 -> q/k (swapped mfma, [n][d] out);
// else -> v ([c][n] out).
// ---------------------------------------------------------------------------
__global__ __launch_bounds__(256) void qkv_mfma_kernel(
    const __bf16* __restrict__ xln_t, const float* __restrict__ w,
    const float* __restrict__ bias, __bf16* __restrict__ qt,
    __bf16* __restrict__ kt, __bf16* __restrict__ vbf) {
  __shared__ __align__(16) __bf16 As[2][64][68];   // 17.0 KiB
  __shared__ __align__(16) __bf16 Bs[2][128][68];  // 34.0 KiB
  int n0 = blockIdx.x * 128;
  bool swap = blockIdx.y < 16;
  int m0 = swap ? blockIdx.y * 64 : 1024 + ((int)blockIdx.y - 16) * 64;
  int b = blockIdx.z;
  int tid = threadIdx.x;
  int wid = tid >> 6, lane = tid & 63;
  int g = lane >> 4, c = lane & 15;
  int wr = wid >> 1, wc = wid & 1;
  const __bf16* xln = xln_t + (size_t)b * NN * CC;
  int arow = tid >> 4, ac4 = tid & 15;
  int brow = tid >> 3, bc8 = tid & 7;

  float4 wA[4];
  bf16x8 xB[4];
  auto LOADREGS = [&](int k0) {
#pragma unroll
    for (int l = 0; l < 4; ++l)
      wA[l] = *(const float4*)&w[(size_t)(m0 + arow + 16 * l) * CC + k0 + ac4 * 4];
#pragma unroll
    for (int l = 0; l < 4; ++l)
      xB[l] = *(const bf16x8*)&xln[(size_t)(n0 + brow + 32 * l) * CC + k0 + bc8 * 8];
  };
  auto STORELDS = [&](int buf) {
#pragma unroll
    for (int l = 0; l < 4; ++l) {
      bf16x4 pk = {(__bf16)wA[l].x, (__bf16)wA[l].y, (__bf16)wA[l].z,
                   (__bf16)wA[l].w};
      *(bf16x4*)&As[buf][arow + 16 * l][ac4 * 4] = pk;
    }
#pragma unroll
    for (int l = 0; l < 4; ++l)
      *(bf16x8*)&Bs[buf][brow + 32 * l][bc8 * 8] = xB[l];
  };

  LOADREGS(0);
  STORELDS(0);
  __syncthreads();
  f32x4 acc[2][4] = {};
  for (int ktile = 0; ktile < 8; ++ktile) {
    int cur = ktile & 1;
    if (ktile < 7) LOADREGS((ktile + 1) * 64);
#pragma unroll
    for (int hh = 0; hh < 2; ++hh) {
      bf16x8 af[2], bfr[4];
#pragma unroll
      for (int mi = 0; mi < 2; ++mi)
        af[mi] = *(const bf16x8*)&As[cur][wr * 32 + mi * 16 + c][hh * 32 + g * 8];
#pragma unroll
      for (int nj = 0; nj < 4; ++nj)
        bfr[nj] = *(const bf16x8*)&Bs[cur][wc * 64 + nj * 16 + c][hh * 32 + g * 8];
      if (swap) {
#pragma unroll
        for (int mi = 0; mi < 2; ++mi)
#pragma unroll
          for (int nj = 0; nj < 4; ++nj)
            acc[mi][nj] = __builtin_amdgcn_mfma_f32_16x16x32_bf16(
                bfr[nj], af[mi], acc[mi][nj], 0, 0, 0);
      } else {
#pragma unroll
        for (int mi = 0; mi < 2; ++mi)
#pragma unroll
          for (int nj = 0; nj < 4; ++nj)
            acc[mi][nj] = __builtin_amdgcn_mfma_f32_16x16x32_bf16(
                af[mi], bfr[nj], acc[mi][nj], 0, 0, 0);
      }
    }
    if (ktile < 7) STORELDS(cur ^ 1);
    __syncthreads();
  }
  if (swap) {
    int obase = m0 + wr * 32;
    int sec = obase >> 9;  // 0=q, 1=k
    int osec = obase & 511;
    int head = osec >> 6;
    int dbase = osec & 63;
    __bf16* dst = (sec == 0 ? qt : kt) + (size_t)(b * NHEADS + head) * NN * HDIM;
    float scl = (sec == 0) ? QSCALE : 1.0f;
#pragma unroll
    for (int mi = 0; mi < 2; ++mi) {
      float bo = bias[obase + mi * 16 + c];
      int d = dbase + mi * 16 + c;
#pragma unroll
      for (int nj = 0; nj < 4; ++nj)
#pragma unroll
        for (int r = 0; r < 4; ++r) {
          int n = n0 + wc * 64 + nj * 16 + 4 * g + r;
          dst[(size_t)n * HDIM + d] = (__bf16)((acc[mi][nj][r] + bo) * scl);
        }
    }
  } else {
#pragma unroll
    for (int mi = 0; mi < 2; ++mi)
#pragma unroll
      for (int r = 0; r < 4; ++r) {
        int o = m0 + wr * 32 + mi * 16 + 4 * g + r;
        int ch = o - 1024;
        float bo = bias[o];
#pragma unroll
        for (int nj = 0; nj < 4; ++nj) {
          int n = n0 + wc * 64 + nj * 16 + c;
          vbf[((size_t)b * CC + ch) * NN + n] = (__bf16)(acc[mi][nj][r] + bo);
        }
      }
  }
}

// ---------------------------------------------------------------------------
// Kernel 3: flash attention, split-KV. 512 threads = 8 waves, QBLK=128,
// each block covers half the KV range (1024 rows) and emits unnormalized
// partials (O f32, m, l). Both QK^T and PV swapped -> lane-local softmax;
// defer-rescale THR=8 (exp2 domain).
// ---------------------------------------------------------------------------
__global__ __launch_bounds__(512, 4) void attn_mfma_kernel(
    const __bf16* __restrict__ qt, const __bf16* __restrict__ ktg,
    const __bf16* __restrict__ vbf, float* __restrict__ opart,
    float* __restrict__ ml) {
  __shared__ __align__(16) __bf16 Kb[2][64][72];  // 18 KiB
  __shared__ __align__(16) __bf16 Vb[2][64][72];  // 18 KiB
  __shared__ __align__(16) __bf16 Ps[128][72];    // 18 KiB
  int tid = threadIdx.x;
  int wid = tid >> 6, lane = tid & 63;
  int g = lane >> 4, c = lane & 15;
  int n0 = blockIdx.x * 128;
  int h = blockIdx.y;
  int b = blockIdx.z >> 1, split = blockIdx.z & 1;
  int bh = b * NHEADS + h;
  const __bf16* qbase = qt + ((size_t)bh * NN + n0) * HDIM;
  const __bf16* kbase = ktg + ((size_t)bh * NN + split * KVHALF) * HDIM;
  const __bf16* vbase = vbf + ((size_t)b * CC + h * HDIM) * NN + split * KVHALF;

  int sr = tid >> 3, sc = (tid & 7) * 8;  // staging: row 0..63, col-start
  bf16x8 kr = *(const bf16x8*)(kbase + (size_t)sr * HDIM + sc);
  bf16x8 vr = *(const bf16x8*)(vbase + (size_t)sr * NN + sc);
  bf16x8 aq0 = *(const bf16x8*)(qbase + (size_t)(wid * 16 + c) * HDIM + g * 8);
  bf16x8 aq1 = *(const bf16x8*)(qbase + (size_t)(wid * 16 + c) * HDIM + 32 + g * 8);
  *(bf16x8*)&Kb[0][sr][sc] = kr;
  *(bf16x8*)&Vb[0][sr][sc] = vr;

  f32x4 O[4] = {};   // O^T: O[dt][r] = O^T[d = dt*16+4g+r][q = c]
  float m_ = -1e30f; // running max for q-row c (uniform across the 4 g-lanes)
  float l_ = 0.f;    // PARTIAL sum (this lane's k-share)
  __syncthreads();

  for (int t = 0; t < KVHALF / 64; ++t) {
    int cur = t & 1;
    bool pf = (t + 1 < KVHALF / 64);
    int mt = (t + 1) * 64;
    if (pf) {
      kr = *(const bf16x8*)(kbase + (size_t)(mt + sr) * HDIM + sc);
      vr = *(const bf16x8*)(vbase + (size_t)sr * NN + mt + sc);
    }
    // ---- QK^T swapped: st[t4][r] = S[q=c][k=16*t4+4*g+r] ----
    f32x4 st[4];
    __builtin_amdgcn_s_setprio(1);
#pragma unroll
    for (int t4 = 0; t4 < 4; ++t4) {
      bf16x8 bk0 = *(const bf16x8*)&Kb[cur][t4 * 16 + c][g * 8];
      bf16x8 bk1 = *(const bf16x8*)&Kb[cur][t4 * 16 + c][32 + g * 8];
      f32x4 acc = {0.f, 0.f, 0.f, 0.f};
      acc = __builtin_amdgcn_mfma_f32_16x16x32_bf16(bk0, aq0, acc, 0, 0, 0);
      acc = __builtin_amdgcn_mfma_f32_16x16x32_bf16(bk1, aq1, acc, 0, 0, 0);
      st[t4] = acc;
    }
    __builtin_amdgcn_s_setprio(0);
    // ---- tile max (row c lane-local; 2 shuffles over the quad) ----
    float pm = st[0][0];
#pragma unroll
    for (int t4 = 0; t4 < 4; ++t4)
#pragma unroll
      for (int r = 0; r < 4; ++r) pm = fmaxf(pm, st[t4][r]);
    pm = fmaxf(pm, __shfl_xor(pm, 16));
    pm = fmaxf(pm, __shfl_xor(pm, 32));
    // ---- defer-rescale ----
    if (!__all(pm <= m_ + 8.0f)) {
      float mn = fmaxf(m_, pm);
      float fs = exp2f(m_ - mn);
      m_ = mn;
      l_ *= fs;
#pragma unroll
      for (int dt = 0; dt < 4; ++dt)
#pragma unroll
        for (int r = 0; r < 4; ++r) O[dt][r] *= fs;
    }
    float ps = 0.f;
#pragma unroll
    for (int t4 = 0; t4 < 4; ++t4) {
      float p0 = exp2f(st[t4][0] - m_);
      float p1 = exp2f(st[t4][1] - m_);
      float p2 = exp2f(st[t4][2] - m_);
      float p3 = exp2f(st[t4][3] - m_);
      ps += (p0 + p1) + (p2 + p3);
      bf16x4 quad = {(__bf16)p0, (__bf16)p1, (__bf16)p2, (__bf16)p3};
      *(bf16x4*)&Ps[wid * 16 + c][t4 * 16 + 4 * g] = quad;
    }
    l_ += ps;
    // ---- PV swapped: O^T += V^T P^T ----
    bf16x8 ap0 = *(const bf16x8*)&Ps[wid * 16 + c][g * 8];
    bf16x8 ap1 = *(const bf16x8*)&Ps[wid * 16 + c][32 + g * 8];
    __builtin_amdgcn_s_setprio(1);
#pragma unroll
    for (int dt = 0; dt < 4; ++dt) {
      bf16x8 bv0 = *(const bf16x8*)&Vb[cur][dt * 16 + c][g * 8];
      bf16x8 bv1 = *(const bf16x8*)&Vb[cur][dt * 16 + c][32 + g * 8];
      O[dt] = __builtin_amdgcn_mfma_f32_16x16x32_bf16(bv0, ap0, O[dt], 0, 0, 0);
      O[dt] = __builtin_amdgcn_mfma_f32_16x16x32_bf16(bv1, ap1, O[dt], 0, 0, 0);
    }
    __builtin_amdgcn_s_setprio(0);
    if (pf) {
      *(bf16x8*)&Kb[cur ^ 1][sr][sc] = kr;
      *(bf16x8*)&Vb[cur ^ 1][sr][sc] = vr;
    }
    __syncthreads();
  }
  // ---- epilogue: unnormalized partials ----
  float lt = l_ + __shfl_xor(l_, 16);
  lt += __shfl_xor(lt, 32);
  size_t prow = ((size_t)(split * BB + b) * NHEADS + h) * NN + (n0 + wid * 16 + c);
#pragma unroll
  for (int dt = 0; dt < 4; ++dt)
    *(f32x4*)&opart[prow * HDIM + dt * 16 + 4 * g] = O[dt];
  if (lane < 16) {
    float2 mlv = {m_, lt};
    *(float2*)&ml[prow * 2] = mlv;
  }
}

// ---------------------------------------------------------------------------
// Kernel 3b: combine the two KV-split partials -> xa_t[b][n][c] bf16.
// ---------------------------------------------------------------------------
__global__ __launch_bounds__(256) void attn_combine_kernel(
    const float* __restrict__ opart, const float* __restrict__ ml,
    __bf16* __restrict__ xa_t) {
  int t = threadIdx.x;
  int row_local = t >> 4;          // 0..15
  int dq = (t & 15) * 4;           // 0..60
  int R = blockIdx.x * 16 + row_local;  // global (b,h,n) row, 0..32767
  int n = R & (NN - 1);
  int bh = R >> 11;
  int b = bh >> 3, h = bh & 7;
  size_t p0 = ((size_t)(0 * BB + b) * NHEADS + h) * NN + n;
  size_t p1 = ((size_t)(1 * BB + b) * NHEADS + h) * NN + n;
  float m0 = ml[p0 * 2], l0 = ml[p0 * 2 + 1];
  float m1 = ml[p1 * 2], l1 = ml[p1 * 2 + 1];
  float m = fmaxf(m0, m1);
  float w0 = exp2f(m0 - m), w1 = exp2f(m1 - m);
  float linv = 1.0f / (l0 * w0 + l1 * w1);
  float4 o0 = *(const float4*)&opart[p0 * HDIM + dq];
  float4 o1 = *(const float4*)&opart[p1 * HDIM + dq];
  bf16x4 pk = {(__bf16)((o0.x * w0 + o1.x * w1) * linv),
               (__bf16)((o0.y * w0 + o1.y * w1) * linv),
               (__bf16)((o0.z * w0 + o1.z * w1) * linv),
               (__bf16)((o0.w * w0 + o1.w * w1) * linv)};
  *(bf16x4*)&xa_t[((size_t)b * NN + n) * CC + h * HDIM + dq] = pk;
}

// ---------------------------------------------------------------------------
// Kernel 4: proj GEMM, reg-staged double-buffered LDS, 1 barrier per K-step,
// bias + residual(normalized x, fp32) epilogue.
// ---------------------------------------------------------------------------
__global__ __launch_bounds__(256) void proj_mfma_kernel(
    const __bf16* __restrict__ xa_t, const float* __restrict__ w,
    const float* __restrict__ bias, const float* __restrict__ x,
    const float* __restrict__ mu, const float* __restrict__ rstd,
    const float* __restrict__ lnw, const float* __restrict__ lnb,
    float* __restrict__ out) {
  __shared__ __align__(16) __bf16 As[2][64][68];
  __shared__ __align__(16) __bf16 Bs[2][64][68];
  int n0 = blockIdx.x * 64;
  int m0 = blockIdx.y * 64;
  int b = blockIdx.z;
  int tid = threadIdx.x;
  int wid = tid >> 6, lane = tid & 63;
  int g = lane >> 4, c = lane & 15;
  int wr = wid >> 1, wc = wid & 1;
  const __bf16* xab = xa_t + (size_t)b * NN * CC;
  int arow = tid >> 4, ac4 = tid & 15;
  int brow = tid >> 3, bc8 = tid & 7;

  float4 wA[4];
  bf16x8 xB[2];
  auto LOADREGS = [&](int k0) {
#pragma unroll
    for (int l = 0; l < 4; ++l)
      wA[l] = *(const float4*)&w[(size_t)(m0 + arow + 16 * l) * CC + k0 + ac4 * 4];
#pragma unroll
    for (int l = 0; l < 2; ++l)
      xB[l] = *(const bf16x8*)&xab[(size_t)(n0 + brow + 32 * l) * CC + k0 + bc8 * 8];
  };
  auto STORELDS = [&](int buf) {
#pragma unroll
    for (int l = 0; l < 4; ++l) {
      bf16x4 pk = {(__bf16)wA[l].x, (__bf16)wA[l].y, (__bf16)wA[l].z,
                   (__bf16)wA[l].w};
      *(bf16x4*)&As[buf][arow + 16 * l][ac4 * 4] = pk;
    }
#pragma unroll
    for (int l = 0; l < 2; ++l)
      *(bf16x8*)&Bs[buf][brow + 32 * l][bc8 * 8] = xB[l];
  };

  LOADREGS(0);
  STORELDS(0);
  __syncthreads();
  f32x4 acc[2][2] = {};
  for (int ktile = 0; ktile < 8; ++ktile) {
    int cur = ktile & 1;
    if (ktile < 7) LOADREGS((ktile + 1) * 64);
#pragma unroll
    for (int hh = 0; hh < 2; ++hh) {
      bf16x8 af[2], bfr[2];
#pragma unroll
      for (int mi = 0; mi < 2; ++mi)
        af[mi] = *(const bf16x8*)&As[cur][wr * 32 + mi * 16 + c][hh * 32 + g * 8];
#pragma unroll
      for (int nj = 0; nj < 2; ++nj)
        bfr[nj] = *(const bf16x8*)&Bs[cur][wc * 32 + nj * 16 + c][hh * 32 + g * 8];
#pragma unroll
      for (int mi = 0; mi < 2; ++mi)
#pragma unroll
        for (int nj = 0; nj < 2; ++nj)
          acc[mi][nj] = __builtin_amdgcn_mfma_f32_16x16x32_bf16(
              af[mi], bfr[nj], acc[mi][nj], 0, 0, 0);
    }
    if (ktile < 7) STORELDS(cur ^ 1);
    __syncthreads();
  }
#pragma unroll
  for (int mi = 0; mi < 2; ++mi)
#pragma unroll
    for (int r = 0; r < 4; ++r) {
      int o = m0 + wr * 32 + mi * 16 + 4 * g + r;
      float bo = bias[o], gw = lnw[o], gb = lnb[o];
#pragma unroll
      for (int nj = 0; nj < 2; ++nj) {
        int n = n0 + wc * 32 + nj * 16 + c;
        int tok = b * NN + n;
        float xv = x[((size_t)b * CC + o) * NN + n];
        float xlnv = (xv - mu[tok]) * rstd[tok] * gw + gb;
        out[((size_t)b * CC + o) * NN + n] = acc[mi][nj][r] + bo + xlnv;
      }
    }
}

// ---------------------------------------------------------------------------
extern "C" void kernel_launch(void* const* d_in, const int* in_sizes, int n_in,
                              void* d_out, int out_size, void* d_ws, size_t ws_size,
                              hipStream_t stream) {
  const float* x = (const float*)d_in[0];
  const float* lnw = (const float*)d_in[1];
  const float* lnb = (const float*)d_in[2];
  const float* wqkv = (const float*)d_in[3];
  const float* bqkv = (const float*)d_in[4];
  const float* wproj = (const float*)d_in[5];
  const float* bproj = (const float*)d_in[6];
  float* out = (float*)d_out;
  (void)in_sizes; (void)n_in; (void)out_size; (void)ws_size;

  char* wsb = (char*)d_ws;
  float* mu = (float*)wsb;                               // 16 KB
  float* rstd = mu + 4096;                               // 16 KB
  const size_t HSZ = (size_t)BB * NHEADS * NN * HDIM;    // 2M elems
  __bf16* qt = (__bf16*)(wsb + 32768);                   // 4 MB
  __bf16* kt = qt + HSZ;                                 // 4 MB
  __bf16* vbf = kt + HSZ;                                // 4 MB
  __bf16* xa_t = vbf + HSZ;                              // 4 MB
  __bf16* xln_t = xa_t + HSZ;                            // 4 MB (dead after qkv)
  // opart overlays xln_t's region and extends: 2 splits x 8 MB f32 = 16 MB
  float* opart = (float*)xln_t;
  float* ml = (float*)(wsb + 32768 + 4 * HSZ * sizeof(__bf16) +
                       (size_t)NSPLIT * HSZ * sizeof(float));  // 256 KB

  hipLaunchKernelGGL(ln_stats_kernel, dim3(256), dim3(256), 0, stream, x, mu, rstd);
  hipLaunchKernelGGL(ln_transpose_kernel, dim3(32, 8, 2), dim3(256), 0, stream,
                     x, mu, rstd, lnw, lnb, xln_t);
  hipLaunchKernelGGL(qkv_mfma_kernel, dim3(16, 24, 2), dim3(256), 0, stream,
                     xln_t, wqkv, bqkv, qt, kt, vbf);
  hipLaunchKernelGGL(attn_mfma_kernel, dim3(16, 8, 4), dim3(512), 0, stream,
                     qt, kt, vbf, opart, ml);
  hipLaunchKernelGGL(attn_combine_kernel, dim3(2048), dim3(256), 0, stream,
                     opart, ml, xa_t);
  hipLaunchKernelGGL(proj_mfma_kernel, dim3(32, 8, 2), dim3(256), 0, stream,
                     xa_t, wproj, bproj, x, mu, rstd, lnw, lnb, out);
}

// Round 8
// 79.453 us; speedup vs baseline: 1.0074x; 1.0074x over previous
//
#include <hip/hip_runtime.h>
#include <hip/hip_bf16.h>

// Problem constants
#define BB 2
#define CC 512
#define NN 2048          // T*H*W = 8*16*16
#define NHEADS 8
#define HDIM 64
#define NSPLIT 2
#define KVHALF 1024      // NN / NSPLIT

typedef __attribute__((ext_vector_type(8))) __bf16 bf16x8;
typedef __attribute__((ext_vector_type(4))) __bf16 bf16x4;
typedef __attribute__((ext_vector_type(2))) __bf16 bf16x2;
typedef __attribute__((ext_vector_type(4))) float f32x4;

#define QSCALE 0.18033688f  // 0.125 * log2(e): QK^T lands in exp2 domain

// ---------------------------------------------------------------------------
// Kernel 1: LayerNorm statistics. 256 blocks x 16 tokens.
// ---------------------------------------------------------------------------
__global__ __launch_bounds__(256) void ln_stats_kernel(
    const float* __restrict__ x, float* __restrict__ mu, float* __restrict__ rstd) {
  __shared__ float rs[16][16];
  __shared__ float rq[16][16];
  int tl = threadIdx.x & 15;   // token within block
  int cg = threadIdx.x >> 4;   // channel group (32 ch each)
  int tok = blockIdx.x * 16 + tl;
  int b = tok >> 11;
  int n = tok & (NN - 1);
  const float* xp = x + (size_t)b * CC * NN + n;
  float s = 0.f, ss = 0.f;
  int c0 = cg * 32;
#pragma unroll 8
  for (int c = c0; c < c0 + 32; ++c) {
    float v = xp[(size_t)c * NN];
    s += v;
    ss += v * v;
  }
  rs[cg][tl] = s;
  rq[cg][tl] = ss;
  __syncthreads();
  if (threadIdx.x < 16) {
    int t = threadIdx.x;
    float S = 0.f, SS = 0.f;
#pragma unroll
    for (int gidx = 0; gidx < 16; ++gidx) {
      S += rs[gidx][t];
      SS += rq[gidx][t];
    }
    float m = S * (1.0f / CC);
    float var = SS * (1.0f / CC) - m * m;
    int tk = blockIdx.x * 16 + t;
    mu[tk] = m;
    rstd[tk] = rsqrtf(var + 1e-5f);
  }
}

// ---------------------------------------------------------------------------
// Kernel 1b: LN apply + transpose: x[b][c][n] fp32 -> xln_t[b][n][c] bf16.
// ---------------------------------------------------------------------------
__global__ __launch_bounds__(256) void ln_transpose_kernel(
    const float* __restrict__ x, const float* __restrict__ mu,
    const float* __restrict__ rstd, const float* __restrict__ lnw,
    const float* __restrict__ lnb, __bf16* __restrict__ xln_t) {
  __shared__ float Xs[64][68];
  int n0 = blockIdx.x * 64;
  int c0 = blockIdx.y * 64;
  int b = blockIdx.z;
  int tid = threadIdx.x;
#pragma unroll
  for (int l = 0; l < 4; ++l) {
    int e = tid + 256 * l;
    int row = e >> 4, c4 = e & 15;
    float4 v = *(const float4*)&x[((size_t)b * CC + c0 + row) * NN + n0 + c4 * 4];
    *(float4*)&Xs[row][c4 * 4] = v;
  }
  __syncthreads();
  int sr = tid >> 2;
  int sc = (tid & 3) * 16;
  int tok = b * NN + n0 + sr;
  float mun = mu[tok], rsn = rstd[tok];
  __bf16 outv[16];
#pragma unroll
  for (int j = 0; j < 16; ++j) {
    int c = c0 + sc + j;
    outv[j] = (__bf16)((Xs[sc + j][sr] - mun) * rsn * lnw[c] + lnb[c]);
  }
  __bf16* dst = &xln_t[((size_t)b * NN + n0 + sr) * CC + c0 + sc];
  *(bf16x8*)&dst[0] = *(bf16x8*)&outv[0];
  *(bf16x8*)&dst[8] = *(bf16x8*)&outv[8];
}

// ---------------------------------------------------------------------------
// Kernel 2: merged QKV GEMM, bf16 MFMA, reg-staged double-buffered LDS,
// ONE barrier per K-step. blockIdx.y<16 -> q/k (swapped mfma, [n][d] out);
// else -> v ([c][n] out).
// ---------------------------------------------------------------------------
__global__ __launch_bounds__(256) void qkv_mfma_kernel(
    const __bf16* __restrict__ xln_t, const float* __restrict__ w,
    const float* __restrict__ bias, __bf16* __restrict__ qt,
    __bf16* __restrict__ kt, __bf16* __restrict__ vbf) {
  __shared__ __align__(16) __bf16 As[2][64][68];   // 17.0 KiB
  __shared__ __align__(16) __bf16 Bs[2][128][68];  // 34.0 KiB
  int n0 = blockIdx.x * 128;
  bool swap = blockIdx.y < 16;
  int m0 = swap ? blockIdx.y * 64 : 1024 + ((int)blockIdx.y - 16) * 64;
  int b = blockIdx.z;
  int tid = threadIdx.x;
  int wid = tid >> 6, lane = tid & 63;
  int g = lane >> 4, c = lane & 15;
  int wr = wid >> 1, wc = wid & 1;
  const __bf16* xln = xln_t + (size_t)b * NN * CC;
  int arow = tid >> 4, ac4 = tid & 15;
  int brow = tid >> 3, bc8 = tid & 7;

  float4 wA[4];
  bf16x8 xB[4];
  auto LOADREGS = [&](int k0) {
#pragma unroll
    for (int l = 0; l < 4; ++l)
      wA[l] = *(const float4*)&w[(size_t)(m0 + arow + 16 * l) * CC + k0 + ac4 * 4];
#pragma unroll
    for (int l = 0; l < 4; ++l)
      xB[l] = *(const bf16x8*)&xln[(size_t)(n0 + brow + 32 * l) * CC + k0 + bc8 * 8];
  };
  auto STORELDS = [&](int buf) {
#pragma unroll
    for (int l = 0; l < 4; ++l) {
      bf16x4 pk = {(__bf16)wA[l].x, (__bf16)wA[l].y, (__bf16)wA[l].z,
                   (__bf16)wA[l].w};
      *(bf16x4*)&As[buf][arow + 16 * l][ac4 * 4] = pk;
    }
#pragma unroll
    for (int l = 0; l < 4; ++l)
      *(bf16x8*)&Bs[buf][brow + 32 * l][bc8 * 8] = xB[l];
  };

  LOADREGS(0);
  STORELDS(0);
  __syncthreads();
  f32x4 acc[2][4] = {};
  for (int ktile = 0; ktile < 8; ++ktile) {
    int cur = ktile & 1;
    if (ktile < 7) LOADREGS((ktile + 1) * 64);
#pragma unroll
    for (int hh = 0; hh < 2; ++hh) {
      bf16x8 af[2], bfr[4];
#pragma unroll
      for (int mi = 0; mi < 2; ++mi)
        af[mi] = *(const bf16x8*)&As[cur][wr * 32 + mi * 16 + c][hh * 32 + g * 8];
#pragma unroll
      for (int nj = 0; nj < 4; ++nj)
        bfr[nj] = *(const bf16x8*)&Bs[cur][wc * 64 + nj * 16 + c][hh * 32 + g * 8];
      if (swap) {
#pragma unroll
        for (int mi = 0; mi < 2; ++mi)
#pragma unroll
          for (int nj = 0; nj < 4; ++nj)
            acc[mi][nj] = __builtin_amdgcn_mfma_f32_16x16x32_bf16(
                bfr[nj], af[mi], acc[mi][nj], 0, 0, 0);
      } else {
#pragma unroll
        for (int mi = 0; mi < 2; ++mi)
#pragma unroll
          for (int nj = 0; nj < 4; ++nj)
            acc[mi][nj] = __builtin_amdgcn_mfma_f32_16x16x32_bf16(
                af[mi], bfr[nj], acc[mi][nj], 0, 0, 0);
      }
    }
    if (ktile < 7) STORELDS(cur ^ 1);
    __syncthreads();
  }
  if (swap) {
    int obase = m0 + wr * 32;
    int sec = obase >> 9;  // 0=q, 1=k
    int osec = obase & 511;
    int head = osec >> 6;
    int dbase = osec & 63;
    __bf16* dst = (sec == 0 ? qt : kt) + (size_t)(b * NHEADS + head) * NN * HDIM;
    float scl = (sec == 0) ? QSCALE : 1.0f;
#pragma unroll
    for (int mi = 0; mi < 2; ++mi) {
      float bo = bias[obase + mi * 16 + c];
      int d = dbase + mi * 16 + c;
#pragma unroll
      for (int nj = 0; nj < 4; ++nj)
#pragma unroll
        for (int r = 0; r < 4; ++r) {
          int n = n0 + wc * 64 + nj * 16 + 4 * g + r;
          dst[(size_t)n * HDIM + d] = (__bf16)((acc[mi][nj][r] + bo) * scl);
        }
    }
  } else {
#pragma unroll
    for (int mi = 0; mi < 2; ++mi)
#pragma unroll
      for (int r = 0; r < 4; ++r) {
        int o = m0 + wr * 32 + mi * 16 + 4 * g + r;
        int ch = o - 1024;
        float bo = bias[o];
#pragma unroll
        for (int nj = 0; nj < 4; ++nj) {
          int n = n0 + wc * 64 + nj * 16 + c;
          vbf[((size_t)b * CC + ch) * NN + n] = (__bf16)(acc[mi][nj][r] + bo);
        }
      }
  }
}

// ---------------------------------------------------------------------------
// Kernel 3: flash attention, split-KV, 512 thr (8 waves), QBLK=128.
// K rows staged PERMUTED in LDS so swapped-QK^T output lands exactly in the
// PV B-fragment layout: P never leaves registers (no LDS bounce, no shuffles).
// Permutation: actual row i -> LDS row (i>>5)<<5 | ((i>>2)&1)<<4 |
// ((i>>3)&3)<<2 | (i&3). Softmax is permutation-invariant; V stays linear.
// ---------------------------------------------------------------------------
__global__ __launch_bounds__(512, 4) void attn_mfma_kernel(
    const __bf16* __restrict__ qt, const __bf16* __restrict__ ktg,
    const __bf16* __restrict__ vbf, float* __restrict__ opart,
    float* __restrict__ ml) {
  __shared__ __align__(16) __bf16 Kb[2][64][72];  // 18 KiB
  __shared__ __align__(16) __bf16 Vb[2][64][72];  // 18 KiB
  int tid = threadIdx.x;
  int wid = tid >> 6, lane = tid & 63;
  int g = lane >> 4, c = lane & 15;
  int n0 = blockIdx.x * 128;
  int h = blockIdx.y;
  int b = blockIdx.z >> 1, split = blockIdx.z & 1;
  int bh = b * NHEADS + h;
  const __bf16* qbase = qt + ((size_t)bh * NN + n0) * HDIM;
  const __bf16* kbase = ktg + ((size_t)bh * NN + split * KVHALF) * HDIM;
  const __bf16* vbase = vbf + ((size_t)b * CC + h * HDIM) * NN + split * KVHALF;

  int sr = tid >> 3, sc = (tid & 7) * 8;  // staging: row 0..63, col-start
  // K destination row permutation (see header comment)
  int psr = ((sr >> 5) << 5) | (((sr >> 2) & 1) << 4) | (((sr >> 3) & 3) << 2) |
            (sr & 3);
  bf16x8 kr = *(const bf16x8*)(kbase + (size_t)sr * HDIM + sc);
  bf16x8 vr = *(const bf16x8*)(vbase + (size_t)sr * NN + sc);
  bf16x8 aq0 = *(const bf16x8*)(qbase + (size_t)(wid * 16 + c) * HDIM + g * 8);
  bf16x8 aq1 = *(const bf16x8*)(qbase + (size_t)(wid * 16 + c) * HDIM + 32 + g * 8);
  *(bf16x8*)&Kb[0][psr][sc] = kr;
  *(bf16x8*)&Vb[0][sr][sc] = vr;

  f32x4 O[4] = {};   // O^T: O[dt][r] = O^T[d = dt*16+4g+r][q = c]
  float m_ = -1e30f; // running max for q-row c (uniform across the 4 g-lanes)
  float l_ = 0.f;    // PARTIAL sum (this lane's k-share)
  __syncthreads();

  for (int t = 0; t < KVHALF / 64; ++t) {
    int cur = t & 1;
    bool pf = (t + 1 < KVHALF / 64);
    int mt = (t + 1) * 64;
    if (pf) {
      kr = *(const bf16x8*)(kbase + (size_t)(mt + sr) * HDIM + sc);
      vr = *(const bf16x8*)(vbase + (size_t)sr * NN + mt + sc);
    }
    // ---- QK^T swapped: st[t4][r] = S[q=c][k = 8g + 4(t4&1) + r + 32(t4>>1)]
    f32x4 st[4];
    __builtin_amdgcn_s_setprio(1);
#pragma unroll
    for (int t4 = 0; t4 < 4; ++t4) {
      bf16x8 bk0 = *(const bf16x8*)&Kb[cur][t4 * 16 + c][g * 8];
      bf16x8 bk1 = *(const bf16x8*)&Kb[cur][t4 * 16 + c][32 + g * 8];
      f32x4 acc = {0.f, 0.f, 0.f, 0.f};
      acc = __builtin_amdgcn_mfma_f32_16x16x32_bf16(bk0, aq0, acc, 0, 0, 0);
      acc = __builtin_amdgcn_mfma_f32_16x16x32_bf16(bk1, aq1, acc, 0, 0, 0);
      st[t4] = acc;
    }
    __builtin_amdgcn_s_setprio(0);
    // ---- tile max (row c lane-local; 2 shuffles over the quad) ----
    float pm = st[0][0];
#pragma unroll
    for (int t4 = 0; t4 < 4; ++t4)
#pragma unroll
      for (int r = 0; r < 4; ++r) pm = fmaxf(pm, st[t4][r]);
    pm = fmaxf(pm, __shfl_xor(pm, 16));
    pm = fmaxf(pm, __shfl_xor(pm, 32));
    // ---- defer-rescale ----
    if (!__all(pm <= m_ + 8.0f)) {
      float mn = fmaxf(m_, pm);
      float fs = exp2f(m_ - mn);
      m_ = mn;
      l_ *= fs;
#pragma unroll
      for (int dt = 0; dt < 4; ++dt)
#pragma unroll
        for (int r = 0; r < 4; ++r) O[dt][r] *= fs;
    }
    // ---- P in registers: pa0 = k 8g..8g+7, pa1 = k 32+8g..32+8g+7 ----
    bf16x8 pa0, pa1;
    float ps = 0.f;
#pragma unroll
    for (int t4 = 0; t4 < 4; ++t4) {
      float p0 = exp2f(st[t4][0] - m_);
      float p1 = exp2f(st[t4][1] - m_);
      float p2 = exp2f(st[t4][2] - m_);
      float p3 = exp2f(st[t4][3] - m_);
      ps += (p0 + p1) + (p2 + p3);
      if (t4 < 2) {
        pa0[(t4 & 1) * 4 + 0] = (__bf16)p0;
        pa0[(t4 & 1) * 4 + 1] = (__bf16)p1;
        pa0[(t4 & 1) * 4 + 2] = (__bf16)p2;
        pa0[(t4 & 1) * 4 + 3] = (__bf16)p3;
      } else {
        pa1[(t4 & 1) * 4 + 0] = (__bf16)p0;
        pa1[(t4 & 1) * 4 + 1] = (__bf16)p1;
        pa1[(t4 & 1) * 4 + 2] = (__bf16)p2;
        pa1[(t4 & 1) * 4 + 3] = (__bf16)p3;
      }
    }
    l_ += ps;
    // ---- PV swapped: O^T += V^T P^T (P straight from registers) ----
    __builtin_amdgcn_s_setprio(1);
#pragma unroll
    for (int dt = 0; dt < 4; ++dt) {
      bf16x8 bv0 = *(const bf16x8*)&Vb[cur][dt * 16 + c][g * 8];
      bf16x8 bv1 = *(const bf16x8*)&Vb[cur][dt * 16 + c][32 + g * 8];
      O[dt] = __builtin_amdgcn_mfma_f32_16x16x32_bf16(bv0, pa0, O[dt], 0, 0, 0);
      O[dt] = __builtin_amdgcn_mfma_f32_16x16x32_bf16(bv1, pa1, O[dt], 0, 0, 0);
    }
    __builtin_amdgcn_s_setprio(0);
    if (pf) {
      *(bf16x8*)&Kb[cur ^ 1][psr][sc] = kr;
      *(bf16x8*)&Vb[cur ^ 1][sr][sc] = vr;
    }
    __syncthreads();
  }
  // ---- epilogue: unnormalized partials ----
  float lt = l_ + __shfl_xor(l_, 16);
  lt += __shfl_xor(lt, 32);
  size_t prow = ((size_t)(split * BB + b) * NHEADS + h) * NN + (n0 + wid * 16 + c);
#pragma unroll
  for (int dt = 0; dt < 4; ++dt)
    *(f32x4*)&opart[prow * HDIM + dt * 16 + 4 * g] = O[dt];
  if (lane < 16) {
    float2 mlv = {m_, lt};
    *(float2*)&ml[prow * 2] = mlv;
  }
}

// ---------------------------------------------------------------------------
// Kernel 3b: combine the two KV-split partials -> xa_t[b][n][c] bf16.
// ---------------------------------------------------------------------------
__global__ __launch_bounds__(256) void attn_combine_kernel(
    const float* __restrict__ opart, const float* __restrict__ ml,
    __bf16* __restrict__ xa_t) {
  int t = threadIdx.x;
  int row_local = t >> 4;          // 0..15
  int dq = (t & 15) * 4;           // 0..60
  int R = blockIdx.x * 16 + row_local;  // global (b,h,n) row, 0..32767
  int n = R & (NN - 1);
  int bh = R >> 11;
  int b = bh >> 3, h = bh & 7;
  size_t p0 = ((size_t)(0 * BB + b) * NHEADS + h) * NN + n;
  size_t p1 = ((size_t)(1 * BB + b) * NHEADS + h) * NN + n;
  float m0 = ml[p0 * 2], l0 = ml[p0 * 2 + 1];
  float m1 = ml[p1 * 2], l1 = ml[p1 * 2 + 1];
  float m = fmaxf(m0, m1);
  float w0 = exp2f(m0 - m), w1 = exp2f(m1 - m);
  float linv = 1.0f / (l0 * w0 + l1 * w1);
  float4 o0 = *(const float4*)&opart[p0 * HDIM + dq];
  float4 o1 = *(const float4*)&opart[p1 * HDIM + dq];
  bf16x4 pk = {(__bf16)((o0.x * w0 + o1.x * w1) * linv),
               (__bf16)((o0.y * w0 + o1.y * w1) * linv),
               (__bf16)((o0.z * w0 + o1.z * w1) * linv),
               (__bf16)((o0.w * w0 + o1.w * w1) * linv)};
  *(bf16x4*)&xa_t[((size_t)b * NN + n) * CC + h * HDIM + dq] = pk;
}

// ---------------------------------------------------------------------------
// Kernel 4: proj GEMM, reg-staged double-buffered LDS, 1 barrier per K-step,
// bias + residual(normalized x, fp32) epilogue.
// ---------------------------------------------------------------------------
__global__ __launch_bounds__(256) void proj_mfma_kernel(
    const __bf16* __restrict__ xa_t, const float* __restrict__ w,
    const float* __restrict__ bias, const float* __restrict__ x,
    const float* __restrict__ mu, const float* __restrict__ rstd,
    const float* __restrict__ lnw, const float* __restrict__ lnb,
    float* __restrict__ out) {
  __shared__ __align__(16) __bf16 As[2][64][68];
  __shared__ __align__(16) __bf16 Bs[2][64][68];
  int n0 = blockIdx.x * 64;
  int m0 = blockIdx.y * 64;
  int b = blockIdx.z;
  int tid = threadIdx.x;
  int wid = tid >> 6, lane = tid & 63;
  int g = lane >> 4, c = lane & 15;
  int wr = wid >> 1, wc = wid & 1;
  const __bf16* xab = xa_t + (size_t)b * NN * CC;
  int arow = tid >> 4, ac4 = tid & 15;
  int brow = tid >> 3, bc8 = tid & 7;

  float4 wA[4];
  bf16x8 xB[2];
  auto LOADREGS = [&](int k0) {
#pragma unroll
    for (int l = 0; l < 4; ++l)
      wA[l] = *(const float4*)&w[(size_t)(m0 + arow + 16 * l) * CC + k0 + ac4 * 4];
#pragma unroll
    for (int l = 0; l < 2; ++l)
      xB[l] = *(const bf16x8*)&xab[(size_t)(n0 + brow + 32 * l) * CC + k0 + bc8 * 8];
  };
  auto STORELDS = [&](int buf) {
#pragma unroll
    for (int l = 0; l < 4; ++l) {
      bf16x4 pk = {(__bf16)wA[l].x, (__bf16)wA[l].y, (__bf16)wA[l].z,
                   (__bf16)wA[l].w};
      *(bf16x4*)&As[buf][arow + 16 * l][ac4 * 4] = pk;
    }
#pragma unroll
    for (int l = 0; l < 2; ++l)
      *(bf16x8*)&Bs[buf][brow + 32 * l][bc8 * 8] = xB[l];
  };

  LOADREGS(0);
  STORELDS(0);
  __syncthreads();
  f32x4 acc[2][2] = {};
  for (int ktile = 0; ktile < 8; ++ktile) {
    int cur = ktile & 1;
    if (ktile < 7) LOADREGS((ktile + 1) * 64);
#pragma unroll
    for (int hh = 0; hh < 2; ++hh) {
      bf16x8 af[2], bfr[2];
#pragma unroll
      for (int mi = 0; mi < 2; ++mi)
        af[mi] = *(const bf16x8*)&As[cur][wr * 32 + mi * 16 + c][hh * 32 + g * 8];
#pragma unroll
      for (int nj = 0; nj < 2; ++nj)
        bfr[nj] = *(const bf16x8*)&Bs[cur][wc * 32 + nj * 16 + c][hh * 32 + g * 8];
#pragma unroll
      for (int mi = 0; mi < 2; ++mi)
#pragma unroll
        for (int nj = 0; nj < 2; ++nj)
          acc[mi][nj] = __builtin_amdgcn_mfma_f32_16x16x32_bf16(
              af[mi], bfr[nj], acc[mi][nj], 0, 0, 0);
    }
    if (ktile < 7) STORELDS(cur ^ 1);
    __syncthreads();
  }
#pragma unroll
  for (int mi = 0; mi < 2; ++mi)
#pragma unroll
    for (int r = 0; r < 4; ++r) {
      int o = m0 + wr * 32 + mi * 16 + 4 * g + r;
      float bo = bias[o], gw = lnw[o], gb = lnb[o];
#pragma unroll
      for (int nj = 0; nj < 2; ++nj) {
        int n = n0 + wc * 32 + nj * 16 + c;
        int tok = b * NN + n;
        float xv = x[((size_t)b * CC + o) * NN + n];
        float xlnv = (xv - mu[tok]) * rstd[tok] * gw + gb;
        out[((size_t)b * CC + o) * NN + n] = acc[mi][nj][r] + bo + xlnv;
      }
    }
}

// ---------------------------------------------------------------------------
extern "C" void kernel_launch(void* const* d_in, const int* in_sizes, int n_in,
                              void* d_out, int out_size, void* d_ws, size_t ws_size,
                              hipStream_t stream) {
  const float* x = (const float*)d_in[0];
  const float* lnw = (const float*)d_in[1];
  const float* lnb = (const float*)d_in[2];
  const float* wqkv = (const float*)d_in[3];
  const float* bqkv = (const float*)d_in[4];
  const float* wproj = (const float*)d_in[5];
  const float* bproj = (const float*)d_in[6];
  float* out = (float*)d_out;
  (void)in_sizes; (void)n_in; (void)out_size; (void)ws_size;

  char* wsb = (char*)d_ws;
  float* mu = (float*)wsb;                               // 16 KB
  float* rstd = mu + 4096;                               // 16 KB
  const size_t HSZ = (size_t)BB * NHEADS * NN * HDIM;    // 2M elems
  __bf16* qt = (__bf16*)(wsb + 32768);                   // 4 MB
  __bf16* kt = qt + HSZ;                                 // 4 MB
  __bf16* vbf = kt + HSZ;                                // 4 MB
  __bf16* xa_t = vbf + HSZ;                              // 4 MB
  __bf16* xln_t = xa_t + HSZ;                            // 4 MB (dead after qkv)
  // opart overlays xln_t's region and extends: 2 splits x 8 MB f32 = 16 MB
  float* opart = (float*)xln_t;
  float* ml = (float*)(wsb + 32768 + 4 * HSZ * sizeof(__bf16) +
                       (size_t)NSPLIT * HSZ * sizeof(float));  // 256 KB

  hipLaunchKernelGGL(ln_stats_kernel, dim3(256), dim3(256), 0, stream, x, mu, rstd);
  hipLaunchKernelGGL(ln_transpose_kernel, dim3(32, 8, 2), dim3(256), 0, stream,
                     x, mu, rstd, lnw, lnb, xln_t);
  hipLaunchKernelGGL(qkv_mfma_kernel, dim3(16, 24, 2), dim3(256), 0, stream,
                     xln_t, wqkv, bqkv, qt, kt, vbf);
  hipLaunchKernelGGL(attn_mfma_kernel, dim3(16, 8, 4), dim3(512), 0, stream,
                     qt, kt, vbf, opart, ml);
  hipLaunchKernelGGL(attn_combine_kernel, dim3(2048), dim3(256), 0, stream,
                     opart, ml, xa_t);
  hipLaunchKernelGGL(proj_mfma_kernel, dim3(32, 8, 2), dim3(256), 0, stream,
                     xa_t, wproj, bproj, x, mu, rstd, lnw, lnb, out);
}